// Round 1
// baseline (236.924 us; speedup 1.0000x reference)
//
#include <hip/hip_runtime.h>
#include <hip/hip_bf16.h>
#include <stdint.h>

#define NN 100000
#define KN 50
#define FIN 128
#define FOUT 128
#define BM 64

typedef __attribute__((ext_vector_type(8))) short bf16x8;
typedef __attribute__((ext_vector_type(4))) float f32x4;

__device__ __forceinline__ uint16_t f2b(float f){
  uint32_t x = __builtin_bit_cast(uint32_t, f);
  x += 0x7fffu + ((x >> 16) & 1u);   // round-to-nearest-even
  return (uint16_t)(x >> 16);
}

// ---- prep: cast x fp32 -> bf16 (halves gather traffic) ----
__global__ void cast_x_kernel(const float* __restrict__ x, uint16_t* __restrict__ xb){
  int i = (blockIdx.x * blockDim.x + threadIdx.x) * 4;
  float4 v = *(const float4*)(x + i);
  ushort4 o;
  o.x = f2b(v.x); o.y = f2b(v.y); o.z = f2b(v.z); o.w = f2b(v.w);
  *(ushort4*)(xb + i) = o;
}

// ---- prep: pack weight [256][128] fp32 -> bf16 in MFMA B-fragment order ----
// B frag for 16x16x32: lane holds B[k = kt*32 + (lane>>4)*8 + i][col = nt*16 + (lane&15)]
__global__ void pack_w_kernel(const float* __restrict__ w, uint16_t* __restrict__ wp){
  int kt = blockIdx.x >> 3, nt = blockIdx.x & 7;
  int lane = threadIdx.x;
  int col = nt * 16 + (lane & 15);
  int k0  = kt * 32 + ((lane >> 4) << 3);
  uint16_t vals[8];
  #pragma unroll
  for (int i = 0; i < 8; i++) vals[i] = f2b(w[(k0 + i) * FOUT + col]);
  *(uint4*)(wp + ((size_t)(kt * 8 + nt) * 64 + lane) * 8) = *(const uint4*)vals;
}

// ---- prep: detect whether neighbors buffer is int32 or int64 ----
// If int64 (values < 2^31), every odd int32 word is 0. Scan first half only
// (stays in bounds for either layout). flag=1 => int32 layout.
__global__ void detect_kernel(const int* __restrict__ nb, int* __restrict__ flag){
  int i = blockIdx.x * blockDim.x + threadIdx.x;
  if (i < NN * KN / 2) {
    if (nb[2 * i + 1] != 0) *flag = 1;
  }
}

// ---- fused: gather+mean -> LDS tile -> MFMA GEMM -> bias+relu ----
__global__ __launch_bounds__(256) void fused_kernel(
    const uint16_t* __restrict__ xb,
    const int* __restrict__ nbrs,
    const uint16_t* __restrict__ wp,
    const float* __restrict__ bias,
    const int* __restrict__ flag,
    float* __restrict__ out)
{
  // row stride 264 bf16 (528B): breaks 512B-stride bank conflicts on A-frag reads
  __shared__ uint16_t h[BM][264];
  const int tid  = threadIdx.x;
  const int wave = tid >> 6, lane = tid & 63;
  const int base = blockIdx.x * BM;
  const int stride_mul = (*flag != 0) ? 1 : 2;  // int64: read low word at 2x index

  // self features: contiguous 16KB copy (nodes in this block are consecutive)
  #pragma unroll
  for (int j = 0; j < 4; j++){
    int ci = j * 256 + tid;
    int r = ci >> 4, c = ci & 15;
    int node = base + r; if (node >= NN) node = NN - 1;
    uint4 v = *(const uint4*)(xb + (size_t)node * FIN + c * 8);
    *(uint4*)(&h[r][c * 8]) = v;
  }

  // aggregate: wave handles 16 rows; lane l accumulates features {2l, 2l+1}
  for (int rr = 0; rr < 16; rr++){
    int r = (wave << 4) + rr;
    int node = base + r;
    int nclamp = node < NN ? node : NN - 1;
    int nb = 0;
    if (lane < KN) nb = nbrs[(nclamp * KN + lane) * stride_mul];
    float s0 = 0.f, s1 = 0.f;
    #pragma unroll 10
    for (int k = 0; k < KN; k++){
      int j = __shfl(nb, k);
      uint32_t v = *(const uint32_t*)(xb + (size_t)j * FIN + lane * 2);
      s0 += __builtin_bit_cast(float, v << 16);
      s1 += __builtin_bit_cast(float, v & 0xffff0000u);
    }
    s0 *= (1.0f / KN); s1 *= (1.0f / KN);
    uint32_t p = (uint32_t)f2b(s0) | ((uint32_t)f2b(s1) << 16);
    *(uint32_t*)(&h[r][FIN + lane * 2]) = p;
  }

  // B fragments: wave w owns cols [w*32, w*32+32), all K. 64 VGPRs, L2-cached loads.
  bf16x8 bfr[8][2];
  #pragma unroll
  for (int kt = 0; kt < 8; kt++)
    #pragma unroll
    for (int ntl = 0; ntl < 2; ntl++){
      int nt = wave * 2 + ntl;
      bfr[kt][ntl] = *(const bf16x8*)(wp + ((size_t)(kt * 8 + nt) * 64 + lane) * 8);
    }

  __syncthreads();

  f32x4 acc[4][2];
  #pragma unroll
  for (int mt = 0; mt < 4; mt++)
    for (int n = 0; n < 2; n++) acc[mt][n] = (f32x4){0.f, 0.f, 0.f, 0.f};

  const int arow = lane & 15;
  const int ak   = (lane >> 4) << 3;
  #pragma unroll
  for (int kt = 0; kt < 8; kt++){
    #pragma unroll
    for (int mt = 0; mt < 4; mt++){
      bf16x8 af = *(const bf16x8*)(&h[mt * 16 + arow][kt * 32 + ak]);
      acc[mt][0] = __builtin_amdgcn_mfma_f32_16x16x32_bf16(af, bfr[kt][0], acc[mt][0], 0, 0, 0);
      acc[mt][1] = __builtin_amdgcn_mfma_f32_16x16x32_bf16(af, bfr[kt][1], acc[mt][1], 0, 0, 0);
    }
  }

  // epilogue: C/D layout col=lane&15, row=(lane>>4)*4+i  [m89]
  #pragma unroll
  for (int ntl = 0; ntl < 2; ntl++){
    int col = wave * 32 + ntl * 16 + (lane & 15);
    float bv = bias[col];
    #pragma unroll
    for (int mt = 0; mt < 4; mt++){
      #pragma unroll
      for (int i = 0; i < 4; i++){
        int row = mt * 16 + ((lane >> 4) << 2) + i;
        int node = base + row;
        if (node < NN){
          float v = acc[mt][ntl][i] + bv;
          out[(size_t)node * FOUT + col] = fmaxf(v, 0.f);
        }
      }
    }
  }
}

extern "C" void kernel_launch(void* const* d_in, const int* in_sizes, int n_in,
                              void* d_out, int out_size, void* d_ws, size_t ws_size,
                              hipStream_t stream){
  const float* x    = (const float*)d_in[0];
  const int*   nbrs = (const int*)d_in[1];
  const float* w    = (const float*)d_in[2];
  const float* bias = (const float*)d_in[3];
  float* out = (float*)d_out;

  uint16_t* xb   = (uint16_t*)d_ws;
  uint16_t* wp   = (uint16_t*)((char*)d_ws + (size_t)NN * FIN * 2);
  int*      flag = (int*)((char*)d_ws + (size_t)NN * FIN * 2 + 65536);

  hipMemsetAsync(flag, 0, 4, stream);
  cast_x_kernel<<<NN * FIN / 4 / 256, 256, 0, stream>>>(x, xb);
  pack_w_kernel<<<64, 64, 0, stream>>>(w, wp);
  detect_kernel<<<(NN * KN / 2 + 255) / 256, 256, 0, stream>>>(nbrs, flag);
  fused_kernel<<<(NN + BM - 1) / BM, 256, 0, stream>>>(xb, nbrs, wp, bias, flag, out);
}

// Round 2
// 134.085 us; speedup vs baseline: 1.7670x; 1.7670x over previous
//
#include <hip/hip_runtime.h>
#include <hip/hip_bf16.h>
#include <stdint.h>

#define NN 100000
#define KN 50
#define FIN 128
#define FOUT 128
#define BM 64

typedef __attribute__((ext_vector_type(8))) short bf16x8;
typedef __attribute__((ext_vector_type(4))) float f32x4;

__device__ __forceinline__ uint16_t f2b(float f){
  uint32_t x = __builtin_bit_cast(uint32_t, f);
  x += 0x7fffu + ((x >> 16) & 1u);   // round-to-nearest-even
  return (uint16_t)(x >> 16);
}

// ---- prep: cast x fp32 -> fp8 e4m3 (HW cvt) for the gather path ----
__global__ void cast_fp8_kernel(const float* __restrict__ x, uint32_t* __restrict__ xf8){
  int i = blockIdx.x * blockDim.x + threadIdx.x;      // one u32 = 4 fp8
  float4 v = *(const float4*)(x + (size_t)i * 4);
  uint32_t p = 0;
  p = __builtin_amdgcn_cvt_pk_fp8_f32(v.x, v.y, p, false);
  p = __builtin_amdgcn_cvt_pk_fp8_f32(v.z, v.w, p, true);
  xf8[i] = p;
}

// ---- prep: pack weight [256][128] fp32 -> bf16 in MFMA B-fragment order ----
__global__ void pack_w_kernel(const float* __restrict__ w, uint16_t* __restrict__ wp){
  int kt = blockIdx.x >> 3, nt = blockIdx.x & 7;
  int lane = threadIdx.x;
  int col = nt * 16 + (lane & 15);
  int k0  = kt * 32 + ((lane >> 4) << 3);
  uint16_t vals[8];
  #pragma unroll
  for (int i = 0; i < 8; i++) vals[i] = f2b(w[(k0 + i) * FOUT + col]);
  *(uint4*)(wp + ((size_t)(kt * 8 + nt) * 64 + lane) * 8) = *(const uint4*)vals;
}

// ---- prep: detect int32 vs int64 neighbors layout ----
__global__ void detect_kernel(const int* __restrict__ nb, int* __restrict__ flag){
  int i = blockIdx.x * blockDim.x + threadIdx.x;
  if (i < NN * KN / 2) {
    if (nb[2 * i + 1] != 0) *flag = 1;
  }
}

// ---- fused: gather(fp8)+mean -> LDS tile -> MFMA GEMM -> bias+relu ----
__global__ __launch_bounds__(256) void fused_kernel(
    const float* __restrict__ x,
    const uint8_t* __restrict__ xf8,
    const int* __restrict__ nbrs,
    const uint16_t* __restrict__ wp,
    const float* __restrict__ bias,
    const int* __restrict__ flag,
    float* __restrict__ out)
{
  __shared__ uint16_t h[BM][264];        // 33792 B, 528B row stride (bank-spread)
  __shared__ int idxs[4][16 * KN];       // 12800 B, per-wave neighbor indices
  const int tid  = threadIdx.x;
  const int wave = tid >> 6, lane = tid & 63;
  const int base = blockIdx.x * BM;
  const int stride_mul = (*flag != 0) ? 1 : 2;   // int64: low dword at 2x index

  // 1) stage this wave's 16 rows x 50 neighbor indices into LDS
  {
    long long fb = (long long)(base + wave * 16) * KN;
    const long long fcap = (long long)NN * KN - 1;
    for (int t = lane; t < 16 * KN; t += 64) {
      long long f = fb + t; if (f > fcap) f = fcap;
      idxs[wave][t] = nbrs[f * stride_mul];
    }
  }

  // 2) self features: x fp32 -> bf16 -> h[r][0..128)
  #pragma unroll
  for (int jj = 0; jj < 8; jj++){
    int ci = jj * 256 + tid;             // 2048 float4 chunks total
    int r = ci >> 5, c = ci & 31;
    int node = base + r; if (node >= NN) node = NN - 1;
    float4 v = *(const float4*)(x + (size_t)node * FIN + c * 4);
    ushort4 o; o.x = f2b(v.x); o.y = f2b(v.y); o.z = f2b(v.z); o.w = f2b(v.w);
    *(ushort4*)(&h[r][c * 4]) = o;
  }

  __syncthreads();

  // 3) gather+mean: lane group g (=lane>>4) owns one row, lane&15 owns 8 features.
  //    One wave-wide dwordx2 load fetches neighbor-k rows for 4 rows at once.
  const int g  = lane >> 4;
  const int fc = (lane & 15) * 8;        // feature base (8 fp8 = 8 bytes)
  for (int rb = 0; rb < 4; rb++){
    int rloc = rb * 4 + g;               // 0..15 within wave
    int r = wave * 16 + rloc;
    const int* ip = &idxs[wave][rloc * KN];
    float acc[8] = {0.f,0.f,0.f,0.f,0.f,0.f,0.f,0.f};
    #pragma unroll 10
    for (int k = 0; k < KN; k++){
      int j = ip[k];                     // ds_read_b32, 4-way group broadcast
      uint2 v = *(const uint2*)(xf8 + (size_t)j * FIN + fc);
      auto f0 = __builtin_amdgcn_cvt_pk_f32_fp8(v.x, false);
      auto f1 = __builtin_amdgcn_cvt_pk_f32_fp8(v.x, true);
      auto f2 = __builtin_amdgcn_cvt_pk_f32_fp8(v.y, false);
      auto f3 = __builtin_amdgcn_cvt_pk_f32_fp8(v.y, true);
      acc[0] += f0[0]; acc[1] += f0[1]; acc[2] += f1[0]; acc[3] += f1[1];
      acc[4] += f2[0]; acc[5] += f2[1]; acc[6] += f3[0]; acc[7] += f3[1];
    }
    uint16_t o[8];
    #pragma unroll
    for (int i = 0; i < 8; i++) o[i] = f2b(acc[i] * (1.0f / KN));
    *(uint4*)(&h[r][FIN + fc]) = *(const uint4*)o;
  }

  // 4) B fragments: wave w owns cols [w*32, w*32+32)
  bf16x8 bfr[8][2];
  #pragma unroll
  for (int kt = 0; kt < 8; kt++)
    #pragma unroll
    for (int ntl = 0; ntl < 2; ntl++){
      int nt = wave * 2 + ntl;
      bfr[kt][ntl] = *(const bf16x8*)(wp + ((size_t)(kt * 8 + nt) * 64 + lane) * 8);
    }

  __syncthreads();

  // 5) GEMM: 64 MFMAs (16x16x32 bf16)
  f32x4 acc[4][2];
  #pragma unroll
  for (int mt = 0; mt < 4; mt++)
    for (int n = 0; n < 2; n++) acc[mt][n] = (f32x4){0.f, 0.f, 0.f, 0.f};

  const int arow = lane & 15;
  const int ak   = (lane >> 4) << 3;
  #pragma unroll
  for (int kt = 0; kt < 8; kt++){
    #pragma unroll
    for (int mt = 0; mt < 4; mt++){
      bf16x8 af = *(const bf16x8*)(&h[mt * 16 + arow][kt * 32 + ak]);
      acc[mt][0] = __builtin_amdgcn_mfma_f32_16x16x32_bf16(af, bfr[kt][0], acc[mt][0], 0, 0, 0);
      acc[mt][1] = __builtin_amdgcn_mfma_f32_16x16x32_bf16(af, bfr[kt][1], acc[mt][1], 0, 0, 0);
    }
  }

  // 6) epilogue: C/D layout col=lane&15, row=(lane>>4)*4+i  [m89]
  #pragma unroll
  for (int ntl = 0; ntl < 2; ntl++){
    int col = wave * 32 + ntl * 16 + (lane & 15);
    float bv = bias[col];
    #pragma unroll
    for (int mt = 0; mt < 4; mt++){
      #pragma unroll
      for (int i = 0; i < 4; i++){
        int row = mt * 16 + ((lane >> 4) << 2) + i;
        int node = base + row;
        if (node < NN){
          float v = acc[mt][ntl][i] + bv;
          out[(size_t)node * FOUT + col] = fmaxf(v, 0.f);
        }
      }
    }
  }
}

extern "C" void kernel_launch(void* const* d_in, const int* in_sizes, int n_in,
                              void* d_out, int out_size, void* d_ws, size_t ws_size,
                              hipStream_t stream){
  const float* x    = (const float*)d_in[0];
  const int*   nbrs = (const int*)d_in[1];
  const float* w    = (const float*)d_in[2];
  const float* bias = (const float*)d_in[3];
  float* out = (float*)d_out;

  uint8_t*  xf8  = (uint8_t*)d_ws;                                   // 12.8 MB
  uint16_t* wp   = (uint16_t*)((char*)d_ws + (size_t)NN * FIN);      // 64 KB
  int*      flag = (int*)((char*)d_ws + (size_t)NN * FIN + 65536);

  hipMemsetAsync(flag, 0, 4, stream);
  cast_fp8_kernel<<<NN * FIN / 4 / 256, 256, 0, stream>>>(x, (uint32_t*)xf8);
  pack_w_kernel<<<64, 64, 0, stream>>>(w, wp);
  detect_kernel<<<(NN * KN / 2 + 255) / 256, 256, 0, stream>>>(nbrs, flag);
  fused_kernel<<<(NN + BM - 1) / BM, 256, 0, stream>>>(x, xf8, nbrs, wp, bias, flag, out);
}

// Round 4
// 123.283 us; speedup vs baseline: 1.9218x; 1.0876x over previous
//
#include <hip/hip_runtime.h>
#include <hip/hip_bf16.h>
#include <stdint.h>

#define NN 100000
#define KN 50
#define FIN 128
#define FOUT 128
#define BM 64

typedef __attribute__((ext_vector_type(8))) short bf16x8;
typedef __attribute__((ext_vector_type(4))) float f32x4;
typedef __attribute__((ext_vector_type(2))) float f32x2;

__device__ __forceinline__ uint16_t f2b(float f){
  uint32_t x = __builtin_bit_cast(uint32_t, f);
  x += 0x7fffu + ((x >> 16) & 1u);   // round-to-nearest-even
  return (uint16_t)(x >> 16);
}

// ---- prep: cast x fp32 -> fp8 e4m3 (HW cvt) for the gather path ----
__global__ void cast_fp8_kernel(const float* __restrict__ x, uint32_t* __restrict__ xf8){
  int i = blockIdx.x * blockDim.x + threadIdx.x;      // one u32 = 4 fp8
  float4 v = *(const float4*)(x + (size_t)i * 4);
  uint32_t p = 0;
  p = __builtin_amdgcn_cvt_pk_fp8_f32(v.x, v.y, p, false);
  p = __builtin_amdgcn_cvt_pk_fp8_f32(v.z, v.w, p, true);
  xf8[i] = p;
}

// ---- prep: pack weight [256][128] fp32 -> bf16 in MFMA B-fragment order ----
__global__ void pack_w_kernel(const float* __restrict__ w, uint16_t* __restrict__ wp){
  int kt = blockIdx.x >> 3, nt = blockIdx.x & 7;
  int lane = threadIdx.x;
  int col = nt * 16 + (lane & 15);
  int k0  = kt * 32 + ((lane >> 4) << 3);
  uint16_t vals[8];
  #pragma unroll
  for (int i = 0; i < 8; i++) vals[i] = f2b(w[(k0 + i) * FOUT + col]);
  *(uint4*)(wp + ((size_t)(kt * 8 + nt) * 64 + lane) * 8) = *(const uint4*)vals;
}

// ---- prep: detect int32 vs int64 neighbors layout (prefix scan is enough) ----
__global__ void detect_kernel(const int* __restrict__ nb, int* __restrict__ flag){
  int i = blockIdx.x * blockDim.x + threadIdx.x;   // 8192 odd words
  if (nb[2 * i + 1] != 0) *flag = 1;
}

// ---- gather+mean: 32 nodes/block, 8-lane groups, dwordx4 fp8 loads ----
__global__ __launch_bounds__(256) void gather_kernel(
    const uint8_t* __restrict__ xf8,
    const int* __restrict__ nbrs,
    const int* __restrict__ flag,
    uint16_t* __restrict__ agg)
{
  __shared__ int idxs[4][8 * KN];            // 6400 B
  const int tid  = threadIdx.x;
  const int wave = tid >> 6, lane = tid & 63;
  const int base = blockIdx.x * 32;          // 32 nodes per block, 8 per wave
  const int stride_mul = (*flag != 0) ? 1 : 2;

  // stage this wave's 8 rows x 50 neighbor indices
  {
    long long fb = (long long)(base + wave * 8) * KN;
    #pragma unroll
    for (int t = lane; t < 8 * KN; t += 64)
      idxs[wave][t] = nbrs[(fb + t) * stride_mul];
  }
  __syncthreads();

  const int g  = lane >> 3;                  // 8 groups of 8 lanes
  const int fl = (lane & 7) * 16;            // 16 fp8 features per lane
  const int node = base + wave * 8 + g;
  const int* ip = &idxs[wave][g * KN];

  f32x2 acc[8];
  #pragma unroll
  for (int i = 0; i < 8; i++) acc[i] = (f32x2){0.f, 0.f};

  #pragma unroll 10
  for (int k = 0; k < KN; k++){
    int j = ip[k];                           // broadcast within 8-lane group
    uint4 v = *(const uint4*)(xf8 + ((size_t)(uint32_t)j << 7) + fl);
    acc[0] += __builtin_amdgcn_cvt_pk_f32_fp8(v.x, false);
    acc[1] += __builtin_amdgcn_cvt_pk_f32_fp8(v.x, true);
    acc[2] += __builtin_amdgcn_cvt_pk_f32_fp8(v.y, false);
    acc[3] += __builtin_amdgcn_cvt_pk_f32_fp8(v.y, true);
    acc[4] += __builtin_amdgcn_cvt_pk_f32_fp8(v.z, false);
    acc[5] += __builtin_amdgcn_cvt_pk_f32_fp8(v.z, true);
    acc[6] += __builtin_amdgcn_cvt_pk_f32_fp8(v.w, false);
    acc[7] += __builtin_amdgcn_cvt_pk_f32_fp8(v.w, true);
  }

  uint16_t o[16];
  #pragma unroll
  for (int i = 0; i < 8; i++){
    o[2*i]   = f2b(acc[i].x * (1.0f / KN));
    o[2*i+1] = f2b(acc[i].y * (1.0f / KN));
  }
  uint16_t* dst = agg + (size_t)node * FIN + fl;   // fl doubles as bf16 elem offset (16 elems)
  *(uint4*)(dst)     = *(const uint4*)(o);
  *(uint4*)(dst + 8) = *(const uint4*)(o + 8);
}

// ---- GEMM: concat(x, agg) @ W + b, relu ----
__global__ __launch_bounds__(256) void gemm_kernel(
    const float* __restrict__ x,
    const uint16_t* __restrict__ agg,
    const uint16_t* __restrict__ wp,
    const float* __restrict__ bias,
    float* __restrict__ out)
{
  __shared__ uint16_t h[BM][264];            // 33792 B
  const int tid  = threadIdx.x;
  const int wave = tid >> 6, lane = tid & 63;
  const int base = blockIdx.x * BM;

  // self features: x fp32 -> bf16 -> h[r][0..128)
  #pragma unroll
  for (int jj = 0; jj < 8; jj++){
    int ci = jj * 256 + tid;                 // 2048 float4 chunks
    int r = ci >> 5, c = ci & 31;
    int node = base + r; if (node >= NN) node = NN - 1;
    float4 v = *(const float4*)(x + (size_t)node * FIN + c * 4);
    ushort4 o2; o2.x = f2b(v.x); o2.y = f2b(v.y); o2.z = f2b(v.z); o2.w = f2b(v.w);
    *(ushort4*)(&h[r][c * 4]) = o2;
  }
  // aggregated features: bf16 copy -> h[r][128..256)
  #pragma unroll
  for (int jj = 0; jj < 4; jj++){
    int ci = jj * 256 + tid;                 // 1024 uint4 chunks
    int r = ci >> 4, c = ci & 15;
    int node = base + r; if (node >= NN) node = NN - 1;
    uint4 v = *(const uint4*)(agg + (size_t)node * FIN + c * 8);
    *(uint4*)(&h[r][FIN + c * 8]) = v;
  }

  // B fragments: wave w owns cols [w*32, w*32+32)
  bf16x8 bfr[8][2];
  #pragma unroll
  for (int kt = 0; kt < 8; kt++)
    #pragma unroll
    for (int ntl = 0; ntl < 2; ntl++){
      int nt = wave * 2 + ntl;
      bfr[kt][ntl] = *(const bf16x8*)(wp + ((size_t)(kt * 8 + nt) * 64 + lane) * 8);
    }

  __syncthreads();

  f32x4 acc[4][2];
  #pragma unroll
  for (int mt = 0; mt < 4; mt++)
    for (int n = 0; n < 2; n++) acc[mt][n] = (f32x4){0.f, 0.f, 0.f, 0.f};

  const int arow = lane & 15;
  const int ak   = (lane >> 4) << 3;
  #pragma unroll
  for (int kt = 0; kt < 8; kt++){
    #pragma unroll
    for (int mt = 0; mt < 4; mt++){
      bf16x8 af = *(const bf16x8*)(&h[mt * 16 + arow][kt * 32 + ak]);
      acc[mt][0] = __builtin_amdgcn_mfma_f32_16x16x32_bf16(af, bfr[kt][0], acc[mt][0], 0, 0, 0);
      acc[mt][1] = __builtin_amdgcn_mfma_f32_16x16x32_bf16(af, bfr[kt][1], acc[mt][1], 0, 0, 0);
    }
  }

  // epilogue: C/D layout col=lane&15, row=(lane>>4)*4+i  [m89]
  #pragma unroll
  for (int ntl = 0; ntl < 2; ntl++){
    int col = wave * 32 + ntl * 16 + (lane & 15);
    float bv = bias[col];
    #pragma unroll
    for (int mt = 0; mt < 4; mt++){
      #pragma unroll
      for (int i = 0; i < 4; i++){
        int row = mt * 16 + ((lane >> 4) << 2) + i;
        int node = base + row;
        if (node < NN){
          float v = acc[mt][ntl][i] + bv;
          out[(size_t)node * FOUT + col] = fmaxf(v, 0.f);
        }
      }
    }
  }
}

extern "C" void kernel_launch(void* const* d_in, const int* in_sizes, int n_in,
                              void* d_out, int out_size, void* d_ws, size_t ws_size,
                              hipStream_t stream){
  const float* x    = (const float*)d_in[0];
  const int*   nbrs = (const int*)d_in[1];
  const float* w    = (const float*)d_in[2];
  const float* bias = (const float*)d_in[3];
  float* out = (float*)d_out;

  uint8_t*  xf8  = (uint8_t*)d_ws;                                        // 12.8 MB
  uint16_t* wp   = (uint16_t*)((char*)d_ws + (size_t)NN * FIN);           // 64 KB
  int*      flag = (int*)((char*)d_ws + (size_t)NN * FIN + 65536);
  uint16_t* agg  = (uint16_t*)((char*)d_ws + (size_t)NN * FIN + 131072);  // 25.6 MB

  (void)hipMemsetAsync(flag, 0, 4, stream);
  cast_fp8_kernel<<<NN * FIN / 4 / 256, 256, 0, stream>>>(x, (uint32_t*)xf8);
  pack_w_kernel<<<64, 64, 0, stream>>>(w, wp);
  detect_kernel<<<32, 256, 0, stream>>>(nbrs, flag);
  gather_kernel<<<NN / 32, 256, 0, stream>>>(xf8, nbrs, flag, agg);
  gemm_kernel<<<(NN + BM - 1) / BM, 256, 0, stream>>>(x, agg, wp, bias, out);
}